// Round 6
// baseline (523.383 us; speedup 1.0000x reference)
//
#include <hip/hip_runtime.h>
#include <hip/hip_bf16.h>

// DynaGraphNet round 6: lane-owns-q attention (no shuffles, no in-loop adjacency).
// B=4, T=48, N=2000, F=16, H=64, HEADS=4(d=16), HOR=24, P=32. fp32 throughout.
// attn2 mask precomputed as BITS: k_adj (a>0 off-diag, via ballot) + k_diag
// (folds diag condition ad > -norm into the bit). Main passes: per-lane q-row
// in registers, broadcast LDS reads of m-rows, softmax w/o max-subtraction
// (linear partials => m-chunks merge by plain sums).

#define NB 4
#define TT 48
#define NNODES 2000
#define HORZ 24
#define PART_Q 8000

#define D4(a,b) ((a).x*(b).x + (a).y*(b).y + (a).z*(b).z + (a).w*(b).w)
#define FMA4(o,p,v) { (o).x = fmaf((p),(v).x,(o).x); (o).y = fmaf((p),(v).y,(o).y); \
                      (o).z = fmaf((p),(v).z,(o).z); (o).w = fmaf((p),(v).w,(o).w); }

__device__ __forceinline__ float wsum64(float v) {
#pragma unroll
    for (int m = 1; m < 64; m <<= 1) v += __shfl_xor(v, m, 64);
    return v;
}

// ---- proj_w [64][768] -> pT4 [jb=192][h=64][4] ----
__global__ __launch_bounds__(256) void k_tr(const float* __restrict__ pw,
                                            float* __restrict__ pT) {
    int i = blockIdx.x * 256 + threadIdx.x;
    int h = i / 768, j = i - h * 768;
    pT[((j >> 2) * 64 + h) * 4 + (j & 3)] = pw[i];
}

// ---- encoder: conv+BN+ReLU+proj+LN+ReLU -> node[g][64] ----
__global__ __launch_bounds__(64) void k_enc(const float* __restrict__ x,
        const float* __restrict__ cw, const float* __restrict__ cb,
        const float* __restrict__ bg, const float* __restrict__ bb,
        const float* __restrict__ pT, const float* __restrict__ pb,
        const float* __restrict__ g1, const float* __restrict__ b1,
        float* __restrict__ node) {
    __shared__ float xs[8][52];
    __shared__ float hs[8][768];
    __shared__ float wc[16][4];
    int tid = threadIdx.x;
    int g0 = blockIdx.x * 8;

    if (tid < 16) {
        float s = bg[tid] * rsqrtf(1.0f + 1e-5f);
        wc[tid][0] = cw[tid * 3 + 0] * s;
        wc[tid][1] = cw[tid * 3 + 1] * s;
        wc[tid][2] = cw[tid * 3 + 2] * s;
        wc[tid][3] = cb[tid] * s + bb[tid];
    }
    for (int i = tid; i < 8 * TT; i += 64) {
        int m = i & 7, t = i >> 3;
        int g = g0 + m;
        int b = g / NNODES, n = g - b * NNODES;
        xs[m][t + 1] = x[(b * TT + t) * NNODES + n];
    }
    if (tid < 8) { xs[tid][0] = 0.f; xs[tid][TT + 1] = 0.f; }
    __syncthreads();

    for (int m = 0; m < 8; m++) {
        for (int j = tid; j < 16 * TT; j += 64) {
            int f = j / TT, t = j - f * TT;
            float h = wc[f][0] * xs[m][t] + wc[f][1] * xs[m][t + 1] +
                      wc[f][2] * xs[m][t + 2] + wc[f][3];
            hs[m][j] = fmaxf(h, 0.f);
        }
    }
    __syncthreads();

    float acc[8];
    float pbv = pb[tid];
#pragma unroll
    for (int m = 0; m < 8; m++) acc[m] = pbv;
    const float4* pT4v = (const float4*)pT;
    for (int jb = 0; jb < 192; ++jb) {
        float4 wv = pT4v[jb * 64 + tid];
#pragma unroll
        for (int m = 0; m < 8; m++) {
            float4 hv = *(const float4*)&hs[m][jb * 4];
            acc[m] += D4(wv, hv);
        }
    }
    float gg = g1[tid], bbv = b1[tid];
    for (int m = 0; m < 8; m++) {
        float v = acc[m];
        float sm = wsum64(v);
        float sq = wsum64(v * v);
        float mu = sm * (1.f / 64.f);
        float var = sq * (1.f / 64.f) - mu * mu;
        float z = (v - mu) * rsqrtf(var + 1e-5f) * gg + bbv;
        node[(g0 + m) * 64 + tid] = fmaxf(z, 0.f);
    }
}

// ---- qkv + src/dst projections, 8-node tile per block ----
__global__ __launch_bounds__(256) void k_qkv(const float* __restrict__ node,
        const float* __restrict__ ipw, const float* __restrict__ ipb,
        const float* __restrict__ sw, const float* __restrict__ sb,
        const float* __restrict__ dw, const float* __restrict__ db,
        float* __restrict__ Qb, float* __restrict__ Kb, float* __restrict__ Vb,
        float* __restrict__ Sb, float* __restrict__ Db) {
    __shared__ float nds[8][64];
    int tid = threadIdx.x;
    int g0 = blockIdx.x * 8;
    for (int i = tid; i < 8 * 64; i += 256) {
        nds[i >> 6][i & 63] = node[(size_t)g0 * 64 + i];
    }
    __syncthreads();

    int o = tid;
    const float* wrow; float bias;
    if (o < 192)      { wrow = ipw + o * 64;          bias = ipb[o]; }
    else if (o < 224) { wrow = sw + (o - 192) * 64;   bias = sb[o - 192]; }
    else              { wrow = dw + (o - 224) * 64;   bias = db[o - 224]; }

    float acc[8];
#pragma unroll
    for (int n = 0; n < 8; ++n) acc[n] = bias;

#pragma unroll
    for (int c = 0; c < 4; ++c) {
        const float4* wp = (const float4*)(wrow + c * 16);
        float4 w0 = wp[0], w1 = wp[1], w2 = wp[2], w3 = wp[3];
#pragma unroll
        for (int n = 0; n < 8; ++n) {
            const float4* nr = (const float4*)&nds[n][c * 16];
            float4 a0 = nr[0], a1 = nr[1], a2 = nr[2], a3 = nr[3];
            acc[n] += D4(a0, w0) + D4(a1, w1) + D4(a2, w2) + D4(a3, w3);
        }
    }

    if (o < 64) {
#pragma unroll
        for (int n = 0; n < 8; ++n) Qb[(size_t)(g0 + n) * 64 + o] = acc[n] * 0.25f;
    } else if (o < 128) {
        int oo = o - 64;
#pragma unroll
        for (int n = 0; n < 8; ++n) Kb[(size_t)(g0 + n) * 64 + oo] = acc[n];
    } else if (o < 192) {
        int oo = o - 128;
#pragma unroll
        for (int n = 0; n < 8; ++n) Vb[(size_t)(g0 + n) * 64 + oo] = acc[n];
    } else if (o < 224) {
        int oo = o - 192;
#pragma unroll
        for (int n = 0; n < 8; ++n) {
            float a = acc[n];
            Sb[(size_t)(g0 + n) * 32 + oo] = (a >= 0.f ? a : 0.2f * a);
        }
    } else {
        int oo = o - 224;
#pragma unroll
        for (int n = 0; n < 8; ++n) {
            float a = acc[n];
            Db[(size_t)(g0 + n) * 32 + oo] = (a >= 0.f ? a : 0.2f * a);
        }
    }
}

// ---- adjacency mask bits: grid 512 = b4 x qt32 x mc4; wave lane = m ----
__global__ __launch_bounds__(256) void k_adj(const float* __restrict__ Sbuf,
        const float* __restrict__ Dbuf, const float* __restrict__ es_p,
        unsigned* __restrict__ maskU, float* __restrict__ ssqP,
        float* __restrict__ adv) {
    __shared__ float Sl[64][32];
    __shared__ float ssqW[4][64];
    int tid = threadIdx.x, bid = blockIdx.x;
    int b = bid >> 7, qt = (bid >> 2) & 31, mc = bid & 3;
    int w = tid >> 6, l = tid & 63;
    int bbase = b * NNODES;
    int qg0 = bbase + qt * 64;
    float es = es_p[0];

    for (int k = 0; k < 2; ++k) {
        int idx = tid + k * 256;              // < 512
        int row = idx >> 3, cc = idx & 7;
        int qv = qt * 64 + row;
        *(float4*)&Sl[row][cc * 4] =
            *(const float4*)(Sbuf + (size_t)(bbase + min(qv, NNODES - 1)) * 32 + cc * 4);
    }
    __syncthreads();

    float ssqAcc = 0.f;
#pragma unroll
    for (int tt = 0; tt < 2; ++tt) {
        int t = w + tt * 4;
        int mtb = mc * 512 + t * 64;
        int mb = mtb + l;
        bool mok = mb < NNODES;
        float4 dr[8];
        const float4* dp = (const float4*)(Dbuf + (size_t)(bbase + (mok ? mb : NNODES - 1)) * 32);
#pragma unroll
        for (int j = 0; j < 8; ++j) dr[j] = dp[j];

        unsigned lo = 0, hi = 0;
        for (int qq = 0; qq < 64; ++qq) {
            int qv = qt * 64 + qq;
            const float4* sp = (const float4*)&Sl[qq][0];
            float a = 0.f;
#pragma unroll
            for (int j = 0; j < 8; ++j) a += D4(sp[j], dr[j]);
            a *= es;
            if (!mok) a = 0.f;
            bool diag = (mb == qv);
            if (diag && qv < NNODES) adv[qg0 + qq - bbase + bbase] = a;   // adv[qg0+qq]
            bool bit = (a > 0.f) && !diag;
            float ssqq = wsum64(a * a);
            unsigned long long bal = __ballot(bit);
            if (qq == l) { lo = (unsigned)bal; hi = (unsigned)(bal >> 32); ssqAcc += ssqq; }
        }
        int qv = qt * 64 + l;
        if (qv < NNODES) {
            int widx = mc * 16 + t * 2;
            maskU[(size_t)widx * PART_Q + qg0 + l] = lo;
            maskU[(size_t)(widx + 1) * PART_Q + qg0 + l] = hi;
        }
    }
    ssqW[w][l] = ssqAcc;
    __syncthreads();
    if (tid < 64) {
        int qv = qt * 64 + tid;
        if (qv < NNODES)
            ssqP[(size_t)mc * PART_Q + qg0 + tid] =
                ssqW[0][tid] + ssqW[1][tid] + ssqW[2][tid] + ssqW[3][tid];
    }
}

// ---- diag fixup: set mask bit m==q iff ad > -norm ----
__global__ __launch_bounds__(256) void k_diag(const float* __restrict__ ssqP,
        const float* __restrict__ adv, unsigned* __restrict__ maskU) {
    int qg = blockIdx.x * 256 + threadIdx.x;
    if (qg >= PART_Q) return;
    float ss = ssqP[qg] + ssqP[PART_Q + qg] + ssqP[2 * PART_Q + qg] + ssqP[3 * PART_Q + qg];
    float norm = fmaxf(sqrtf(ss), 1e-12f);
    float ad = adv[qg];
    if (ad > -norm) {
        int qloc = qg % NNODES;
        size_t idx = (size_t)(qloc >> 5) * PART_Q + qg;
        maskU[idx] |= (1u << (qloc & 31));
    }
}

// ---- attn1 fused partials: lane owns q; grid 512 = b4 x qb8 x mc16 (125 m) ----
__global__ __launch_bounds__(256, 2) void k_a1(const float* __restrict__ Qb,
        const float* __restrict__ Kb, const float* __restrict__ Vb,
        float* __restrict__ Part) {
    __shared__ float Kl[125][64];
    __shared__ float Vl[125][64];
    int tid = threadIdx.x, bid = blockIdx.x;
    int b = bid >> 7, qb = (bid >> 4) & 7, mc = bid & 15;
    int bbase = b * NNODES;
    int qloc = qb * 256 + tid;
    int qg = bbase + qloc;
    int qi = bbase + min(qloc, NNODES - 1);

    for (int k = 0; k < 16; ++k) {
        int idx = tid + k * 256;              // < 4096, need < 4000
        if (idx < 4000) {
            int arr = idx >= 2000 ? 1 : 0;
            int e = arr ? idx - 2000 : idx;   // < 2000 = 125*16
            int r = e >> 4, cc = e & 15;
            int mb = mc * 125 + r;
            float4 v = *(const float4*)((arr ? Vb : Kb) + (size_t)(bbase + mb) * 64 + cc * 4);
            float* dst = arr ? &Vl[0][0] : &Kl[0][0];
            *(float4*)(dst + r * 64 + cc * 4) = v;
        }
    }

    float4 q[16];
    const float4* qp = (const float4*)(Qb + (size_t)qi * 64);
#pragma unroll
    for (int j = 0; j < 16; ++j) q[j] = qp[j];
    float4 fo[16];
#pragma unroll
    for (int j = 0; j < 16; ++j) fo[j] = make_float4(0.f, 0.f, 0.f, 0.f);
    float sm[4] = {0.f, 0.f, 0.f, 0.f};
    __syncthreads();

    for (int mi = 0; mi < 125; ++mi) {
        const float4* kr = (const float4*)&Kl[mi][0];
        float p[4];
#pragma unroll
        for (int h = 0; h < 4; ++h) {
            float4 k0 = kr[h * 4], k1 = kr[h * 4 + 1], k2 = kr[h * 4 + 2], k3 = kr[h * 4 + 3];
            float s = D4(q[h * 4], k0) + D4(q[h * 4 + 1], k1) +
                      D4(q[h * 4 + 2], k2) + D4(q[h * 4 + 3], k3);
            p[h] = __expf(s);
            sm[h] += p[h];
        }
        const float4* vr = (const float4*)&Vl[mi][0];
#pragma unroll
        for (int j = 0; j < 16; ++j) {
            float4 v = vr[j];
            FMA4(fo[j], p[j >> 2], v)
        }
    }

    if (qloc < NNODES) {
        float* base = Part + (size_t)(mc * 68) * PART_Q + qg;
#pragma unroll
        for (int j = 0; j < 16; ++j) {
            base[(size_t)(4 * j + 0) * PART_Q] = fo[j].x;
            base[(size_t)(4 * j + 1) * PART_Q] = fo[j].y;
            base[(size_t)(4 * j + 2) * PART_Q] = fo[j].z;
            base[(size_t)(4 * j + 3) * PART_Q] = fo[j].w;
        }
#pragma unroll
        for (int h = 0; h < 4; ++h) base[(size_t)(64 + h) * PART_Q] = sm[h];
    }
}

// ---- attn1 merge + out-proj: lane owns q; grid 32 ----
__global__ __launch_bounds__(256) void k_a1m(const float* __restrict__ Part,
        const float* __restrict__ ow, const float* __restrict__ ob,
        float* __restrict__ y1) {
    __shared__ float owl[64][64];
    int tid = threadIdx.x;
    for (int i = tid; i < 4096; i += 256) ((float*)owl)[i] = ow[i];
    __syncthreads();
    int qg = blockIdx.x * 256 + tid;
    if (qg >= PART_Q) return;
    float acc[68];
#pragma unroll
    for (int k = 0; k < 68; ++k) acc[k] = 0.f;
    for (int mc = 0; mc < 16; ++mc) {
        const float* p = Part + (size_t)(mc * 68) * PART_Q + qg;
#pragma unroll
        for (int k = 0; k < 68; ++k) acc[k] += p[(size_t)k * PART_Q];
    }
#pragma unroll
    for (int e = 0; e < 64; ++e) acc[e] /= acc[64 + (e >> 4)];
    float* yo = y1 + (size_t)qg * 64;
    for (int d = 0; d < 64; d += 4) {
        float4 r;
        float rr[4];
#pragma unroll
        for (int u = 0; u < 4; ++u) {
            float s = ob[d + u];
            const float4* wr = (const float4*)&owl[d + u][0];
#pragma unroll
            for (int e4 = 0; e4 < 16; ++e4) {
                float4 w4 = wr[e4];
                s = fmaf(acc[e4 * 4 + 0], w4.x, s);
                s = fmaf(acc[e4 * 4 + 1], w4.y, s);
                s = fmaf(acc[e4 * 4 + 2], w4.z, s);
                s = fmaf(acc[e4 * 4 + 3], w4.w, s);
            }
            rr[u] = s;
        }
        r = make_float4(rr[0], rr[1], rr[2], rr[3]);
        *(float4*)(yo + d) = r;
    }
}

// ---- attn2 fused partials: lane owns q; grid 512 = b4 x qb8 x mc16 (128 m) ----
__global__ __launch_bounds__(256, 2) void k_a2(const float* __restrict__ y1,
        const unsigned* __restrict__ maskU, float* __restrict__ Part) {
    __shared__ float Yl[128][64];
    int tid = threadIdx.x, bid = blockIdx.x;
    int b = bid >> 7, qb = (bid >> 4) & 7, mc = bid & 15;
    int bbase = b * NNODES;
    int qloc = qb * 256 + tid;
    int qg = bbase + qloc;
    int qgc = bbase + min(qloc, NNODES - 1);

    for (int k = 0; k < 8; ++k) {
        int idx = tid + k * 256;              // < 2048 = 128*16
        int r = idx >> 4, cc = idx & 15;
        int mb = mc * 128 + r;
        float4 v = make_float4(0.f, 0.f, 0.f, 0.f);
        if (mb < NNODES)
            v = *(const float4*)(y1 + (size_t)(bbase + mb) * 64 + cc * 4);
        *(float4*)&Yl[r][cc * 4] = v;
    }

    float4 yq[16];
    const float4* qp = (const float4*)(y1 + (size_t)qgc * 64);
#pragma unroll
    for (int j = 0; j < 16; ++j) yq[j] = qp[j];
    float4 o[16];
#pragma unroll
    for (int j = 0; j < 16; ++j) o[j] = make_float4(0.f, 0.f, 0.f, 0.f);
    float sum = 0.f;
    unsigned mw = 0;
    __syncthreads();

    for (int mi = 0; mi < 128; ++mi) {
        if ((mi & 31) == 0) mw = maskU[(size_t)(mc * 4 + (mi >> 5)) * PART_Q + qgc];
        const float4* yr4 = (const float4*)&Yl[mi][0];
        float4 yr[16];
#pragma unroll
        for (int j = 0; j < 16; ++j) yr[j] = yr4[j];
        float s0 = 0.f, s1 = 0.f, s2 = 0.f, s3 = 0.f;
#pragma unroll
        for (int j = 0; j < 4; ++j) {
            s0 += D4(yq[j], yr[j]);
            s1 += D4(yq[4 + j], yr[4 + j]);
            s2 += D4(yq[8 + j], yr[8 + j]);
            s3 += D4(yq[12 + j], yr[12 + j]);
        }
        float s = (s0 + s1) + (s2 + s3);
        float p = ((mw >> (mi & 31)) & 1u) ? __expf(s * 0.125f) : 0.f;
        sum += p;
#pragma unroll
        for (int j = 0; j < 16; ++j) FMA4(o[j], p, yr[j])
    }

    if (qloc < NNODES) {
        float* base = Part + (size_t)(mc * 68) * PART_Q + qg;
#pragma unroll
        for (int j = 0; j < 16; ++j) {
            base[(size_t)(4 * j + 0) * PART_Q] = o[j].x;
            base[(size_t)(4 * j + 1) * PART_Q] = o[j].y;
            base[(size_t)(4 * j + 2) * PART_Q] = o[j].z;
            base[(size_t)(4 * j + 3) * PART_Q] = o[j].w;
        }
        base[(size_t)64 * PART_Q] = sum;
    }
}

// ---- attn2 merge: residual + LN + predictor; lane owns q; grid 32 ----
__global__ __launch_bounds__(256) void k_a2m(const float* __restrict__ Part,
        const float* __restrict__ node,
        const float* __restrict__ ga, const float* __restrict__ ba,
        const float* __restrict__ pw, const float* __restrict__ pb,
        float* __restrict__ out) {
    __shared__ float pwl[24][64];
    __shared__ float gal[64], bal[64], pbl[24];
    int tid = threadIdx.x;
    for (int i = tid; i < 24 * 64; i += 256) ((float*)pwl)[i] = pw[i];
    if (tid < 64) { gal[tid] = ga[tid]; bal[tid] = ba[tid]; }
    if (tid < 24) pbl[tid] = pb[tid];
    __syncthreads();
    int qg = blockIdx.x * 256 + tid;
    if (qg >= PART_Q) return;

    float acc[65];
#pragma unroll
    for (int k = 0; k < 65; ++k) acc[k] = 0.f;
    for (int mc = 0; mc < 16; ++mc) {
        const float* p = Part + (size_t)(mc * 68) * PART_Q + qg;
#pragma unroll
        for (int k = 0; k < 65; ++k) acc[k] += p[(size_t)k * PART_Q];
    }
    float inv = 1.0f / acc[64];
    const float* nd = node + (size_t)qg * 64;
    float oo[64];
    float s1 = 0.f, s2 = 0.f;
#pragma unroll
    for (int d = 0; d < 64; ++d) {
        float v = acc[d] * inv + nd[d];
        oo[d] = v;
        s1 += v; s2 += v * v;
    }
    float mu = s1 * (1.f / 64.f);
    float var = s2 * (1.f / 64.f) - mu * mu;
    float rs = rsqrtf(var + 1e-5f);
#pragma unroll
    for (int d = 0; d < 64; ++d) oo[d] = (oo[d] - mu) * rs * gal[d] + bal[d];

    float* op = out + (size_t)qg * HORZ;
    for (int r = 0; r < HORZ; ++r) {
        float s = pbl[r];
        const float4* wr = (const float4*)&pwl[r][0];
#pragma unroll
        for (int e4 = 0; e4 < 16; ++e4) {
            float4 w4 = wr[e4];
            s = fmaf(oo[e4 * 4 + 0], w4.x, s);
            s = fmaf(oo[e4 * 4 + 1], w4.y, s);
            s = fmaf(oo[e4 * 4 + 2], w4.z, s);
            s = fmaf(oo[e4 * 4 + 3], w4.w, s);
        }
        op[r] = s;
    }
}

extern "C" void kernel_launch(void* const* d_in, const int* in_sizes, int n_in,
                              void* d_out, int out_size, void* d_ws, size_t ws_size,
                              hipStream_t stream) {
    const float* x      = (const float*)d_in[0];
    const float* conv_w = (const float*)d_in[1];
    const float* conv_b = (const float*)d_in[2];
    const float* bn_g   = (const float*)d_in[3];
    const float* bn_b   = (const float*)d_in[4];
    const float* proj_w = (const float*)d_in[5];
    const float* proj_b = (const float*)d_in[6];
    const float* ln1_g  = (const float*)d_in[7];
    const float* ln1_b  = (const float*)d_in[8];
    const float* src_w  = (const float*)d_in[9];
    const float* src_b  = (const float*)d_in[10];
    const float* dst_w  = (const float*)d_in[11];
    const float* dst_b  = (const float*)d_in[12];
    const float* edge_s = (const float*)d_in[13];
    const float* ipw    = (const float*)d_in[14];
    const float* ipb    = (const float*)d_in[15];
    const float* out_w  = (const float*)d_in[16];
    const float* out_b  = (const float*)d_in[17];
    const float* lnA_g  = (const float*)d_in[18];
    const float* lnA_b  = (const float*)d_in[19];
    const float* pred_w = (const float*)d_in[20];
    const float* pred_b = (const float*)d_in[21];
    float* out = (float*)d_out;

    float* ws = (float*)d_ws;
    float*    projT = ws;                       //   49152
    float*    node  = projT + 49152;            //  512000
    float*    y1    = node + 512000;            //  512000
    float*    Qb    = y1 + 512000;              //  512000
    float*    Kb    = Qb + 512000;              //  512000
    float*    Vb    = Kb + 512000;              //  512000
    float*    Sbuf  = Vb + 512000;              //  256000
    float*    Dbuf  = Sbuf + 256000;            //  256000
    unsigned* maskU = (unsigned*)(Dbuf + 256000); // 64*8000 u32 = 512000
    float*    ssqP  = (float*)(maskU + 512000); //   32000
    float*    adv   = ssqP + 32000;             //    8000
    float*    Part  = adv + 8000;               // 16*68*8000 = 8704000

    k_tr<<<192, 256, 0, stream>>>(proj_w, projT);
    k_enc<<<1000, 64, 0, stream>>>(x, conv_w, conv_b, bn_g, bn_b,
                                   projT, proj_b, ln1_g, ln1_b, node);
    k_qkv<<<1000, 256, 0, stream>>>(node, ipw, ipb, src_w, src_b, dst_w, dst_b,
                                    Qb, Kb, Vb, Sbuf, Dbuf);
    k_adj<<<512, 256, 0, stream>>>(Sbuf, Dbuf, edge_s, maskU, ssqP, adv);
    k_diag<<<32, 256, 0, stream>>>(ssqP, adv, maskU);
    k_a1<<<512, 256, 0, stream>>>(Qb, Kb, Vb, Part);
    k_a1m<<<32, 256, 0, stream>>>(Part, out_w, out_b, y1);
    k_a2<<<512, 256, 0, stream>>>(y1, maskU, Part);
    k_a2m<<<32, 256, 0, stream>>>(Part, node, lnA_g, lnA_b, pred_w, pred_b, out);
}